// Round 9
// baseline (358.260 us; speedup 1.0000x reference)
//
#include <hip/hip_runtime.h>

#define F 256
#define TWO_F 512
#define BM 128
#define BN 64
#define BK 64

typedef __attribute__((ext_vector_type(8))) short short8;
typedef __attribute__((ext_vector_type(4))) float float4v;

// ---------- bf16 helpers ----------
static __device__ __forceinline__ unsigned short f2bf(float f) {
    unsigned u = __float_as_uint(f);
    u += 0x7FFFu + ((u >> 16) & 1u);
    return (unsigned short)(u >> 16);
}
static __device__ __forceinline__ unsigned pack2(float lo, float hi) {
    unsigned a = __float_as_uint(lo) + 0x8000u;
    unsigned b = __float_as_uint(hi) + 0x8000u;
    return __builtin_amdgcn_perm(b, a, 0x07060302u);
}
static __device__ __forceinline__ float blo(unsigned u) { return __uint_as_float(u << 16); }
static __device__ __forceinline__ float rawf(unsigned u) { return __uint_as_float(u); }

// ---------- kernel 1: prep (h->hb, W1->Wb, both k-rotated) + zero hist bins ----------
__global__ __launch_bounds__(256) void prep_kernel(
    const float* __restrict__ h, const float* __restrict__ W1,
    unsigned short* __restrict__ hb, unsigned short* __restrict__ Wb,
    int* __restrict__ bins, int M)
{
    int i = blockIdx.x * blockDim.x + threadIdx.x;
    if (i < M * 128) {
        int m = i >> 7;
        int kp = (i & 127) * 2;
        float2 v = *(const float2*)(h + (size_t)m * F + kp);
        unsigned pk = pack2(v.x, v.y);
        int ksw = ((kp & 63) + (m & 7) * 8) & 63;
        *(unsigned*)(hb + (size_t)m * F + (kp & ~63) + ksw) = pk;
    }
    if (i < TWO_F * F) {
        int n = i >> 8;
        int k = i & 255;
        float v = W1[(n & 255) * TWO_F + ((n >> 8) << 8) + k];
        int kin_sw = ((k & 63) + (n & 7) * 8) & 63;
        Wb[n * F + (k & ~63) + kin_sw] = f2bf(v);
    }
    if (i < M) bins[i] = 0;
}

// ---------- kernel 2: histogram of src ----------
__global__ __launch_bounds__(256) void hist_kernel(
    const int* __restrict__ src, int* __restrict__ bins, int E)
{
    int i = blockIdx.x * blockDim.x + threadIdx.x;
    if (i < E) atomicAdd(&bins[src[i]], 1);
}

// ---------- kernel 3: exclusive scan (single block, 1024 threads) -> cursor ----------
__global__ __launch_bounds__(1024) void scan_kernel(
    const int* __restrict__ bins, int* __restrict__ cursor, int M)
{
    __shared__ int part[1024];
    const int t = threadIdx.x;
    const int chunk = (M + 1023) / 1024;
    const int lo = t * chunk;
    const int hi = (lo + chunk < M) ? lo + chunk : M;
    int s = 0;
    for (int i = lo; i < hi; ++i) s += bins[i];
    part[t] = s;
    __syncthreads();
    for (int off = 1; off < 1024; off <<= 1) {
        int v = (t >= off) ? part[t - off] : 0;
        __syncthreads();
        part[t] += v;
        __syncthreads();
    }
    int run = (t > 0) ? part[t - 1] : 0;
    for (int i = lo; i < hi; ++i) { cursor[i] = run; run += bins[i]; }
}

// ---------- kernel 4: GEMM (R7 exact — measured best) ----------
__global__ __launch_bounds__(256, 4) void gemm_kernel(
    const unsigned short* __restrict__ hb, const unsigned short* __restrict__ Wb,
    const float* __restrict__ b1v, unsigned short* __restrict__ C, int M)
{
    __shared__ unsigned short sA[BM * BK];
    __shared__ unsigned short sB[BN * BK];

    const int ib = blockIdx.x;
    const int r8 = ib & 7;
    const int q  = ib >> 3;
    const int by = q & 7;
    const int bx = (q >> 3) * 8 + r8;
    const int bm = bx * BM;
    if (bm >= M) return;
    const int bn = by * BN;

    const int tid  = threadIdx.x;
    const int lane = tid & 63;
    const int wid  = tid >> 6;
    const int st_r = lane >> 3;
    const int st_k = (lane & 7) * 8;
    const int quad = lane >> 4;
    const int l15  = lane & 15;
    const int rot  = (l15 & 7) * 8;

    float4v acc[2][4];
    #pragma unroll
    for (int i = 0; i < 2; ++i)
        #pragma unroll
        for (int j = 0; j < 4; ++j) acc[i][j] = (float4v)(0.f);

    for (int k0 = 0; k0 < F; k0 += BK) {
        #pragma unroll
        for (int p = 0; p < 4; ++p) {
            int r = wid * 32 + p * 8;
            int am = bm + r + st_r; if (am > M - 1) am = M - 1;
            const unsigned short* ga = hb + (size_t)am * F + k0 + st_k;
            __builtin_amdgcn_global_load_lds(
                (const __attribute__((address_space(1))) unsigned int*)ga,
                (__attribute__((address_space(3))) unsigned int*)&sA[r * BK],
                16, 0, 0);
        }
        #pragma unroll
        for (int p = 0; p < 2; ++p) {
            int r = wid * 16 + p * 8;
            const unsigned short* gb = Wb + (size_t)(bn + r + st_r) * F + k0 + st_k;
            __builtin_amdgcn_global_load_lds(
                (const __attribute__((address_space(1))) unsigned int*)gb,
                (__attribute__((address_space(3))) unsigned int*)&sB[r * BK],
                16, 0, 0);
        }
        __syncthreads();

        #pragma unroll
        for (int ks = 0; ks < 2; ++ks) {
            const int koff = (ks * 32 + quad * 8 + rot) & 63;
            short8 afr[2], bfr[4];
            #pragma unroll
            for (int mt = 0; mt < 2; ++mt)
                afr[mt] = *(const short8*)&sA[(wid * 32 + mt * 16 + l15) * BK + koff];
            #pragma unroll
            for (int nt = 0; nt < 4; ++nt)
                bfr[nt] = *(const short8*)&sB[(nt * 16 + l15) * BK + koff];
            #pragma unroll
            for (int mt = 0; mt < 2; ++mt)
                #pragma unroll
                for (int nt = 0; nt < 4; ++nt)
                    acc[mt][nt] = __builtin_amdgcn_mfma_f32_16x16x32_bf16(
                        afr[mt], bfr[nt], acc[mt][nt], 0, 0, 0);
        }
        __syncthreads();
    }

    float bias[4];
    #pragma unroll
    for (int nt = 0; nt < 4; ++nt) {
        int n = bn + nt * 16 + l15;
        bias[nt] = (n < F) ? b1v[n] : 0.f;
    }
    #pragma unroll
    for (int mt = 0; mt < 2; ++mt) {
        int gm0 = bm + wid * 32 + mt * 16 + quad * 4;
        #pragma unroll
        for (int rr = 0; rr < 4; ++rr) {
            int gm = gm0 + rr;
            if (gm < M) {
                unsigned short* cp = C + (size_t)gm * TWO_F + bn + l15;
                #pragma unroll
                for (int nt = 0; nt < 4; ++nt)
                    cp[nt * 16] = f2bf(acc[mt][nt][rr] + bias[nt]);
            }
        }
    }
}

// ---------- kernel 5: scatter edges into src-grouped order ----------
__global__ __launch_bounds__(256) void scatter_kernel(
    const int* __restrict__ src, const int* __restrict__ dst,
    int* __restrict__ cursor, int4* __restrict__ grouped, int E)
{
    int i = blockIdx.x * blockDim.x + threadIdx.x;
    if (i >= E) return;
    int s = src[i];
    int pos = atomicAdd(&cursor[s], 1);
    grouped[pos] = make_int4(s, dst[i], i, 0);
}

// ---------- kernel 6: per-edge score over grouped list (R4 arithmetic, frozen) ----------
__global__ __launch_bounds__(256) void edge_kernel(
    const unsigned short* __restrict__ C,
    const int4* __restrict__ grouped,
    const float* __restrict__ w2,
    const float* __restrict__ b2, float* __restrict__ out, int E)
{
    const int lane = threadIdx.x & 31;
    const int g = blockIdx.x * 8 + (threadIdx.x >> 5);
    const int e0 = g * 2;
    if (e0 >= E) return;
    int4 t0 = grouped[e0];
    int4 t1 = grouped[e0 + 1];

    uint4 av0 = *(const uint4*)(C + (size_t)t0.x * TWO_F + lane * 8);
    uint4 bv0 = *(const uint4*)(C + (size_t)t0.y * TWO_F + F + lane * 8);
    uint4 av1 = *(const uint4*)(C + (size_t)t1.x * TWO_F + lane * 8);
    uint4 bv1 = *(const uint4*)(C + (size_t)t1.y * TWO_F + F + lane * 8);
    float4 w0 = *(const float4*)(w2 + lane * 8);
    float4 w1 = *(const float4*)(w2 + lane * 8 + 4);

    float sum0, sum1;
    sum0  = w0.x * fmaxf(blo(av0.x) + blo(bv0.x), 0.f);
    sum0 += w0.y * fmaxf(rawf(av0.x) + rawf(bv0.x), 0.f);
    sum0 += w0.z * fmaxf(blo(av0.y) + blo(bv0.y), 0.f);
    sum0 += w0.w * fmaxf(rawf(av0.y) + rawf(bv0.y), 0.f);
    sum0 += w1.x * fmaxf(blo(av0.z) + blo(bv0.z), 0.f);
    sum0 += w1.y * fmaxf(rawf(av0.z) + rawf(bv0.z), 0.f);
    sum0 += w1.z * fmaxf(blo(av0.w) + blo(bv0.w), 0.f);
    sum0 += w1.w * fmaxf(rawf(av0.w) + rawf(bv0.w), 0.f);

    sum1  = w0.x * fmaxf(blo(av1.x) + blo(bv1.x), 0.f);
    sum1 += w0.y * fmaxf(rawf(av1.x) + rawf(bv1.x), 0.f);
    sum1 += w0.z * fmaxf(blo(av1.y) + blo(bv1.y), 0.f);
    sum1 += w0.w * fmaxf(rawf(av1.y) + rawf(bv1.y), 0.f);
    sum1 += w1.x * fmaxf(blo(av1.z) + blo(bv1.z), 0.f);
    sum1 += w1.y * fmaxf(rawf(av1.z) + rawf(bv1.z), 0.f);
    sum1 += w1.z * fmaxf(blo(av1.w) + blo(bv1.w), 0.f);
    sum1 += w1.w * fmaxf(rawf(av1.w) + rawf(bv1.w), 0.f);

    #pragma unroll
    for (int off = 16; off > 0; off >>= 1) {
        sum0 += __shfl_down(sum0, off, 32);
        sum1 += __shfl_down(sum1, off, 32);
    }

    if (lane == 0) {
        float b = b2[0];
        out[t0.z] = sum0 + b;
        out[t1.z] = sum1 + b;
    }
}

extern "C" void kernel_launch(void* const* d_in, const int* in_sizes, int n_in,
                              void* d_out, int out_size, void* d_ws, size_t ws_size,
                              hipStream_t stream) {
    const float* h    = (const float*)d_in[0];
    const int*   src  = (const int*)d_in[1];
    const int*   dst  = (const int*)d_in[2];
    const float* W1_w = (const float*)d_in[3];
    const float* W1_b = (const float*)d_in[4];
    const float* W2_w = (const float*)d_in[5];
    const float* W2_b = (const float*)d_in[6];
    float* out = (float*)d_out;

    const int M = in_sizes[0] / F;   // 50000
    const int E = in_sizes[1];       // 800000

    // ws layout (78.5 MB, unchanged footprint):
    //   [Wb bf16 256KB][pad to 512KB]
    //   [hb bf16 25.6MB  -- dead after gemm; grouped int4 (12.8MB) overlays it]
    //   [bins M ints][cursor M ints]   (in the 26MB pad tail)
    //   [C bf16 51.2MB]
    char* ws = (char*)d_ws;
    unsigned short* Wb = (unsigned short*)ws;
    unsigned short* hb = (unsigned short*)(ws + 512 * 1024);
    int4* grouped      = (int4*)(ws + 512 * 1024);                    // overlays hb (after gemm)
    int* bins          = (int*)(ws + 512 * 1024 + (size_t)M * F * 2);
    int* cursor        = bins + M;
    unsigned short* C  = (unsigned short*)(ws + 512 * 1024 + 26 * 1024 * 1024);

    int prep_threads = M * 128 > TWO_F * F ? M * 128 : TWO_F * F;
    prep_kernel<<<(prep_threads + 255) / 256, 256, 0, stream>>>(h, W1_w, hb, Wb, bins, M);

    hist_kernel<<<(E + 255) / 256, 256, 0, stream>>>(src, bins, E);
    scan_kernel<<<1, 1024, 0, stream>>>(bins, cursor, M);

    int nbx = ((M + BM - 1) / BM + 7) / 8 * 8;     // 392
    gemm_kernel<<<nbx * 8, 256, 0, stream>>>(hb, Wb, W1_b, C, M);

    scatter_kernel<<<(E + 255) / 256, 256, 0, stream>>>(src, dst, cursor, grouped, E);

    edge_kernel<<<(E / 2 + 7) / 8, 256, 0, stream>>>(C, grouped, W2_w, W2_b, out, E);
}

// Round 11
// 301.588 us; speedup vs baseline: 1.1879x; 1.1879x over previous
//
#include <hip/hip_runtime.h>

#define F 256
#define TWO_F 512
#define BM 128
#define BN 64
#define BK 64

typedef __attribute__((ext_vector_type(8))) short short8;
typedef __attribute__((ext_vector_type(4))) float float4v;
typedef __attribute__((ext_vector_type(4))) unsigned uint4v;

// ---------- bf16 helpers ----------
static __device__ __forceinline__ unsigned short f2bf(float f) {
    unsigned u = __float_as_uint(f);
    u += 0x7FFFu + ((u >> 16) & 1u);
    return (unsigned short)(u >> 16);
}
static __device__ __forceinline__ unsigned pack2(float lo, float hi) {
    unsigned a = __float_as_uint(lo) + 0x8000u;
    unsigned b = __float_as_uint(hi) + 0x8000u;
    return __builtin_amdgcn_perm(b, a, 0x07060302u);
}
static __device__ __forceinline__ float blo(unsigned u) { return __uint_as_float(u << 16); }
static __device__ __forceinline__ float rawf(unsigned u) { return __uint_as_float(u); }

// meta layout (ints): [0..7] gcnt, [8..16] start (9), [17..24] cursor
#define MT_GCNT 0
#define MT_START 8
#define MT_CURSOR 17

// ---------- kernel 1: prep (h->hb, W1->Wb, k-rotated) + zero bucket counters ----------
__global__ __launch_bounds__(256) void prep_kernel(
    const float* __restrict__ h, const float* __restrict__ W1,
    unsigned short* __restrict__ hb, unsigned short* __restrict__ Wb,
    int* __restrict__ meta, int M)
{
    int i = blockIdx.x * blockDim.x + threadIdx.x;
    if (i < M * 128) {
        int m = i >> 7;
        int kp = (i & 127) * 2;
        float2 v = *(const float2*)(h + (size_t)m * F + kp);
        unsigned pk = pack2(v.x, v.y);
        int ksw = ((kp & 63) + (m & 7) * 8) & 63;
        *(unsigned*)(hb + (size_t)m * F + (kp & ~63) + ksw) = pk;
    }
    if (i < TWO_F * F) {
        int n = i >> 8;
        int k = i & 255;
        float v = W1[(n & 255) * TWO_F + ((n >> 8) << 8) + k];
        int kin_sw = ((k & 63) + (n & 7) * 8) & 63;
        Wb[n * F + (k & ~63) + kin_sw] = f2bf(v);
    }
    if (i < 8) meta[MT_GCNT + i] = 0;
}

// ---------- kernel 2: count edges per dst-bucket (8 buckets = XCD slices) ----------
__global__ __launch_bounds__(256) void count_kernel(
    const int* __restrict__ dst, int* __restrict__ meta, int E, int NB)
{
    __shared__ int lcnt[8];
    const int t = threadIdx.x;
    if (t < 8) lcnt[t] = 0;
    __syncthreads();
    int i = blockIdx.x * 256 + t;
    if (i < E) atomicAdd(&lcnt[dst[i] / NB], 1);
    __syncthreads();
    if (t < 8 && lcnt[t] > 0) atomicAdd(&meta[MT_GCNT + t], lcnt[t]);
}

// ---------- kernel 3: tiny 8-element exclusive scan -> start[9], cursor[8] ----------
__global__ void cursor_kernel(int* __restrict__ meta)
{
    if (threadIdx.x == 0) {
        int run = 0;
        for (int x = 0; x < 8; ++x) {
            meta[MT_START + x] = run;
            meta[MT_CURSOR + x] = run;
            run += meta[MT_GCNT + x];
        }
        meta[MT_START + 8] = run;
    }
}

// ---------- kernel 4: GEMM (R7 exact — measured best) ----------
__global__ __launch_bounds__(256, 4) void gemm_kernel(
    const unsigned short* __restrict__ hb, const unsigned short* __restrict__ Wb,
    const float* __restrict__ b1v, unsigned short* __restrict__ C, int M)
{
    __shared__ unsigned short sA[BM * BK];
    __shared__ unsigned short sB[BN * BK];

    const int ib = blockIdx.x;
    const int r8 = ib & 7;
    const int q  = ib >> 3;
    const int by = q & 7;
    const int bx = (q >> 3) * 8 + r8;
    const int bm = bx * BM;
    if (bm >= M) return;
    const int bn = by * BN;

    const int tid  = threadIdx.x;
    const int lane = tid & 63;
    const int wid  = tid >> 6;
    const int st_r = lane >> 3;
    const int st_k = (lane & 7) * 8;
    const int quad = lane >> 4;
    const int l15  = lane & 15;
    const int rot  = (l15 & 7) * 8;

    float4v acc[2][4];
    #pragma unroll
    for (int i = 0; i < 2; ++i)
        #pragma unroll
        for (int j = 0; j < 4; ++j) acc[i][j] = (float4v)(0.f);

    for (int k0 = 0; k0 < F; k0 += BK) {
        #pragma unroll
        for (int p = 0; p < 4; ++p) {
            int r = wid * 32 + p * 8;
            int am = bm + r + st_r; if (am > M - 1) am = M - 1;
            const unsigned short* ga = hb + (size_t)am * F + k0 + st_k;
            __builtin_amdgcn_global_load_lds(
                (const __attribute__((address_space(1))) unsigned int*)ga,
                (__attribute__((address_space(3))) unsigned int*)&sA[r * BK],
                16, 0, 0);
        }
        #pragma unroll
        for (int p = 0; p < 2; ++p) {
            int r = wid * 16 + p * 8;
            const unsigned short* gb = Wb + (size_t)(bn + r + st_r) * F + k0 + st_k;
            __builtin_amdgcn_global_load_lds(
                (const __attribute__((address_space(1))) unsigned int*)gb,
                (__attribute__((address_space(3))) unsigned int*)&sB[r * BK],
                16, 0, 0);
        }
        __syncthreads();

        #pragma unroll
        for (int ks = 0; ks < 2; ++ks) {
            const int koff = (ks * 32 + quad * 8 + rot) & 63;
            short8 afr[2], bfr[4];
            #pragma unroll
            for (int mt = 0; mt < 2; ++mt)
                afr[mt] = *(const short8*)&sA[(wid * 32 + mt * 16 + l15) * BK + koff];
            #pragma unroll
            for (int nt = 0; nt < 4; ++nt)
                bfr[nt] = *(const short8*)&sB[(nt * 16 + l15) * BK + koff];
            #pragma unroll
            for (int mt = 0; mt < 2; ++mt)
                #pragma unroll
                for (int nt = 0; nt < 4; ++nt)
                    acc[mt][nt] = __builtin_amdgcn_mfma_f32_16x16x32_bf16(
                        afr[mt], bfr[nt], acc[mt][nt], 0, 0, 0);
        }
        __syncthreads();
    }

    float bias[4];
    #pragma unroll
    for (int nt = 0; nt < 4; ++nt) {
        int n = bn + nt * 16 + l15;
        bias[nt] = (n < F) ? b1v[n] : 0.f;
    }
    #pragma unroll
    for (int mt = 0; mt < 2; ++mt) {
        int gm0 = bm + wid * 32 + mt * 16 + quad * 4;
        #pragma unroll
        for (int rr = 0; rr < 4; ++rr) {
            int gm = gm0 + rr;
            if (gm < M) {
                unsigned short* cp = C + (size_t)gm * TWO_F + bn + l15;
                #pragma unroll
                for (int nt = 0; nt < 4; ++nt)
                    cp[nt * 16] = f2bf(acc[mt][nt][rr] + bias[nt]);
            }
        }
    }
}

// ---------- kernel 5: scatter edges into dst-bucket order, int2-packed ----------
__global__ __launch_bounds__(256) void scatter_kernel(
    const int* __restrict__ src, const int* __restrict__ dst,
    int* __restrict__ meta, int2* __restrict__ grouped, int E, int NB)
{
    __shared__ int lcnt[8];
    __shared__ int lbase[8];
    const int t = threadIdx.x;
    if (t < 8) lcnt[t] = 0;
    __syncthreads();
    int i = blockIdx.x * 256 + t;
    int b = 0, rank = 0, s = 0, d = 0;
    bool ok = (i < E);
    if (ok) {
        s = src[i]; d = dst[i];
        b = d / NB;
        rank = atomicAdd(&lcnt[b], 1);
    }
    __syncthreads();
    if (t < 8 && lcnt[t] > 0) lbase[t] = atomicAdd(&meta[MT_CURSOR + t], lcnt[t]);
    __syncthreads();
    if (ok) {
        int pos = lbase[b] + rank;
        grouped[pos] = make_int2((s << 16) | d, i);
    }
}

// ---------- kernel 6: per-edge score over bucketed list; block pinned to bucket via %8 ----------
// dst rows of bucket x live in XCD x's L2 (3.2 MB slice); src rows loaded nontemporal.
__global__ __launch_bounds__(256) void edge_kernel(
    const unsigned short* __restrict__ C,
    const int2* __restrict__ grouped, const int* __restrict__ meta,
    const float* __restrict__ w2,
    const float* __restrict__ b2, float* __restrict__ out)
{
    const int x  = blockIdx.x & 7;
    const int bi = blockIdx.x >> 3;
    const int stx = meta[MT_START + x];
    const int endx = meta[MT_START + x + 1];
    const int lane = threadIdx.x & 31;
    const int e0 = stx + bi * 16 + (threadIdx.x >> 5) * 2;
    if (e0 >= endx) return;
    int2 t0 = grouped[e0];
    bool has1 = (e0 + 1 < endx);
    int2 t1 = has1 ? grouped[e0 + 1] : t0;
    const int s0 = ((unsigned)t0.x) >> 16, d0 = t0.x & 0xFFFF;
    const int s1 = ((unsigned)t1.x) >> 16, d1 = t1.x & 0xFFFF;

    uint4v av0 = __builtin_nontemporal_load((const uint4v*)(C + (size_t)s0 * TWO_F + lane * 8));
    uint4v bv0 = *(const uint4v*)(C + (size_t)d0 * TWO_F + F + lane * 8);
    uint4v av1 = __builtin_nontemporal_load((const uint4v*)(C + (size_t)s1 * TWO_F + lane * 8));
    uint4v bv1 = *(const uint4v*)(C + (size_t)d1 * TWO_F + F + lane * 8);
    float4 w0 = *(const float4*)(w2 + lane * 8);
    float4 w1 = *(const float4*)(w2 + lane * 8 + 4);

    float sum0, sum1;
    sum0  = w0.x * fmaxf(blo(av0.x) + blo(bv0.x), 0.f);
    sum0 += w0.y * fmaxf(rawf(av0.x) + rawf(bv0.x), 0.f);
    sum0 += w0.z * fmaxf(blo(av0.y) + blo(bv0.y), 0.f);
    sum0 += w0.w * fmaxf(rawf(av0.y) + rawf(bv0.y), 0.f);
    sum0 += w1.x * fmaxf(blo(av0.z) + blo(bv0.z), 0.f);
    sum0 += w1.y * fmaxf(rawf(av0.z) + rawf(bv0.z), 0.f);
    sum0 += w1.z * fmaxf(blo(av0.w) + blo(bv0.w), 0.f);
    sum0 += w1.w * fmaxf(rawf(av0.w) + rawf(bv0.w), 0.f);

    sum1  = w0.x * fmaxf(blo(av1.x) + blo(bv1.x), 0.f);
    sum1 += w0.y * fmaxf(rawf(av1.x) + rawf(bv1.x), 0.f);
    sum1 += w0.z * fmaxf(blo(av1.y) + blo(bv1.y), 0.f);
    sum1 += w0.w * fmaxf(rawf(av1.y) + rawf(bv1.y), 0.f);
    sum1 += w1.x * fmaxf(blo(av1.z) + blo(bv1.z), 0.f);
    sum1 += w1.y * fmaxf(rawf(av1.z) + rawf(bv1.z), 0.f);
    sum1 += w1.z * fmaxf(blo(av1.w) + blo(bv1.w), 0.f);
    sum1 += w1.w * fmaxf(rawf(av1.w) + rawf(bv1.w), 0.f);

    #pragma unroll
    for (int off = 16; off > 0; off >>= 1) {
        sum0 += __shfl_down(sum0, off, 32);
        sum1 += __shfl_down(sum1, off, 32);
    }

    if (lane == 0) {
        float b = b2[0];
        out[t0.y] = sum0 + b;
        if (has1) out[t1.y] = sum1 + b;
    }
}

extern "C" void kernel_launch(void* const* d_in, const int* in_sizes, int n_in,
                              void* d_out, int out_size, void* d_ws, size_t ws_size,
                              hipStream_t stream) {
    const float* h    = (const float*)d_in[0];
    const int*   src  = (const int*)d_in[1];
    const int*   dst  = (const int*)d_in[2];
    const float* W1_w = (const float*)d_in[3];
    const float* W1_b = (const float*)d_in[4];
    const float* W2_w = (const float*)d_in[5];
    const float* W2_b = (const float*)d_in[6];
    float* out = (float*)d_out;

    const int M = in_sizes[0] / F;   // 50000
    const int E = in_sizes[1];       // 800000
    const int NB = (M + 7) / 8;      // bucket width (6250)

    // ws layout (77.7 MB):
    //  [Wb 256KB][pad to 512KB]
    //  [hb 25.6MB  -- dead after gemm; grouped int2 (6.4MB) overlays it]
    //  [meta ints in the 26MB-region tail]
    //  [C 51.2MB]
    char* ws = (char*)d_ws;
    unsigned short* Wb = (unsigned short*)ws;
    unsigned short* hb = (unsigned short*)(ws + 512 * 1024);
    int2* grouped      = (int2*)(ws + 512 * 1024);
    int* meta          = (int*)(ws + 512 * 1024 + (size_t)M * F * 2);
    unsigned short* C  = (unsigned short*)(ws + 512 * 1024 + 26 * 1024 * 1024);

    int prep_threads = M * 128 > TWO_F * F ? M * 128 : TWO_F * F;
    prep_kernel<<<(prep_threads + 255) / 256, 256, 0, stream>>>(h, W1_w, hb, Wb, meta, M);

    count_kernel<<<(E + 255) / 256, 256, 0, stream>>>(dst, meta, E, NB);
    cursor_kernel<<<1, 64, 0, stream>>>(meta);

    int nbx = ((M + BM - 1) / BM + 7) / 8 * 8;     // 392
    gemm_kernel<<<nbx * 8, 256, 0, stream>>>(hb, Wb, W1_b, C, M);

    scatter_kernel<<<(E + 255) / 256, 256, 0, stream>>>(src, dst, meta, grouped, E, NB);

    // 8 buckets x Bmax blocks (16 edges/block); generous margin over E/8 for bucket skew
    int Bmax = (E / 8 + 16384 + 15) / 16;
    edge_kernel<<<8 * Bmax, 256, 0, stream>>>(C, grouped, meta, W2_w, W2_b, out);
}

// Round 12
// 229.348 us; speedup vs baseline: 1.5621x; 1.3150x over previous
//
#include <hip/hip_runtime.h>

#define F 256
#define TWO_F 512
#define BM 128
#define BN 64
#define BK 64

typedef __attribute__((ext_vector_type(8))) short short8;
typedef __attribute__((ext_vector_type(4))) float float4v;

// ---------- bf16 helpers ----------
static __device__ __forceinline__ unsigned short f2bf(float f) {
    unsigned u = __float_as_uint(f);
    u += 0x7FFFu + ((u >> 16) & 1u);
    return (unsigned short)(u >> 16);
}
static __device__ __forceinline__ unsigned pack2(float lo, float hi) {
    unsigned a = __float_as_uint(lo) + 0x8000u;
    unsigned b = __float_as_uint(hi) + 0x8000u;
    return __builtin_amdgcn_perm(b, a, 0x07060302u);
}
static __device__ __forceinline__ float blo(unsigned u) { return __uint_as_float(u << 16); }
static __device__ __forceinline__ float rawf(unsigned u) { return __uint_as_float(u); }

// ---------- kernel 1: prep (h->hb, W1->Wb, both k-rotated) ----------
// rotation: within each 64-elem k-block, elem k -> (k + (row&7)*8) & 63
__global__ __launch_bounds__(256) void prep_kernel(
    const float* __restrict__ h, const float* __restrict__ W1,
    unsigned short* __restrict__ hb, unsigned short* __restrict__ Wb, int M)
{
    int i = blockIdx.x * blockDim.x + threadIdx.x;
    if (i < M * 128) {
        int m = i >> 7;
        int kp = (i & 127) * 2;
        float2 v = *(const float2*)(h + (size_t)m * F + kp);
        unsigned pk = pack2(v.x, v.y);
        int ksw = ((kp & 63) + (m & 7) * 8) & 63;
        *(unsigned*)(hb + (size_t)m * F + (kp & ~63) + ksw) = pk;
    }
    if (i < TWO_F * F) {
        int n = i >> 8;
        int k = i & 255;
        float v = W1[(n & 255) * TWO_F + ((n >> 8) << 8) + k];
        int kin_sw = ((k & 63) + (n & 7) * 8) & 63;
        Wb[n * F + (k & ~63) + kin_sw] = f2bf(v);
    }
}

// ---------- kernel 2: GEMM, double-buffered LDS + raw barrier + fine vmcnt ----------
// C[m][n] = sum_k hb[m][k]*Wb[n][k] (+b1 for n<256), bf16 out.
// 4 K-iters; iters k+2 prefetched while computing k -> no vmcnt(0) drains.
__global__ __launch_bounds__(256, 3) void gemm_kernel(
    const unsigned short* __restrict__ hb, const unsigned short* __restrict__ Wb,
    const float* __restrict__ b1v, unsigned short* __restrict__ C, int M)
{
    __shared__ unsigned short sA[2][BM * BK];   // 2 x 16 KB
    __shared__ unsigned short sB[2][BN * BK];   // 2 x  8 KB

    // XCD pairing: all 8 by-blocks of one bx share (ib&7) -> same XCD -> h strip L2-reused 8x.
    const int ib = blockIdx.x;
    const int r8 = ib & 7;
    const int q  = ib >> 3;
    const int by = q & 7;
    const int bx = (q >> 3) * 8 + r8;
    const int bm = bx * BM;
    if (bm >= M) return;
    const int bn = by * BN;

    const int tid  = threadIdx.x;
    const int lane = tid & 63;
    const int wid  = tid >> 6;
    const int st_r = lane >> 3;
    const int st_k = (lane & 7) * 8;
    const int quad = lane >> 4;
    const int l15  = lane & 15;
    const int rot  = (l15 & 7) * 8;

    // 6 global_load_lds issues per call (4 sA + 2 sB) -> vmcnt +6
    auto issue = [&](int k0, int buf) {
        #pragma unroll
        for (int p = 0; p < 4; ++p) {
            int r = wid * 32 + p * 8;
            int am = bm + r + st_r; if (am > M - 1) am = M - 1;   // clamp; stores guarded
            const unsigned short* ga = hb + (size_t)am * F + k0 + st_k;
            __builtin_amdgcn_global_load_lds(
                (const __attribute__((address_space(1))) unsigned int*)ga,
                (__attribute__((address_space(3))) unsigned int*)&sA[buf][r * BK],
                16, 0, 0);
        }
        #pragma unroll
        for (int p = 0; p < 2; ++p) {
            int r = wid * 16 + p * 8;
            const unsigned short* gb = Wb + (size_t)(bn + r + st_r) * F + k0 + st_k;
            __builtin_amdgcn_global_load_lds(
                (const __attribute__((address_space(1))) unsigned int*)gb,
                (__attribute__((address_space(3))) unsigned int*)&sB[buf][r * BK],
                16, 0, 0);
        }
    };

    float4v acc[2][4];
    #pragma unroll
    for (int i = 0; i < 2; ++i)
        #pragma unroll
        for (int j = 0; j < 4; ++j) acc[i][j] = (float4v)(0.f);

    issue(0, 0);
    issue(64, 1);

    #pragma unroll
    for (int it = 0; it < 4; ++it) {
        // wait only for the oldest 6 loads (this iter's buffer); keep prefetch in flight
        if (it == 3) asm volatile("s_waitcnt vmcnt(0)" ::: "memory");
        else         asm volatile("s_waitcnt vmcnt(6)" ::: "memory");
        __builtin_amdgcn_s_barrier();
        asm volatile("" ::: "memory");

        const int buf = it & 1;
        #pragma unroll
        for (int ks = 0; ks < 2; ++ks) {
            const int koff = (ks * 32 + quad * 8 + rot) & 63;
            short8 afr[2], bfr[4];
            #pragma unroll
            for (int mt = 0; mt < 2; ++mt)
                afr[mt] = *(const short8*)&sA[buf][(wid * 32 + mt * 16 + l15) * BK + koff];
            #pragma unroll
            for (int nt = 0; nt < 4; ++nt)
                bfr[nt] = *(const short8*)&sB[buf][(nt * 16 + l15) * BK + koff];
            #pragma unroll
            for (int mt = 0; mt < 2; ++mt)
                #pragma unroll
                for (int nt = 0; nt < 4; ++nt)
                    acc[mt][nt] = __builtin_amdgcn_mfma_f32_16x16x32_bf16(
                        afr[mt], bfr[nt], acc[mt][nt], 0, 0, 0);
        }

        if (it < 2) {
            // all waves done reading buf (ds_read results consumed by MFMA => lgkm drained);
            // cheap rendezvous before DMA overwrites it
            asm volatile("" ::: "memory");
            __builtin_amdgcn_s_barrier();
            asm volatile("" ::: "memory");
            issue((it + 2) * 64, buf);
        }
    }

    // epilogue: +b1 for the n<256 half, bf16 store
    float bias[4];
    #pragma unroll
    for (int nt = 0; nt < 4; ++nt) {
        int n = bn + nt * 16 + l15;
        bias[nt] = (n < F) ? b1v[n] : 0.f;
    }
    #pragma unroll
    for (int mt = 0; mt < 2; ++mt) {
        int gm0 = bm + wid * 32 + mt * 16 + quad * 4;
        #pragma unroll
        for (int rr = 0; rr < 4; ++rr) {
            int gm = gm0 + rr;
            if (gm < M) {
                unsigned short* cp = C + (size_t)gm * TWO_F + bn + l15;
                #pragma unroll
                for (int nt = 0; nt < 4; ++nt)
                    cp[nt * 16] = f2bf(acc[mt][nt][rr] + bias[nt]);
            }
        }
    }
}

// ---------- kernel 3: per-edge score, 2 edges per 32-lane group (measured-best, frozen) ----------
__global__ __launch_bounds__(256) void edge_kernel(
    const unsigned short* __restrict__ C,
    const int* __restrict__ src, const int* __restrict__ dst,
    const float* __restrict__ w2,
    const float* __restrict__ b2, float* __restrict__ out, int E)
{
    const int lane = threadIdx.x & 31;
    const int g = blockIdx.x * 8 + (threadIdx.x >> 5);
    const int e0 = g * 2;
    if (e0 >= E) return;
    const int s0 = src[e0], d0 = dst[e0];
    const int s1 = src[e0 + 1], d1 = dst[e0 + 1];

    uint4 av0 = *(const uint4*)(C + (size_t)s0 * TWO_F + lane * 8);
    uint4 bv0 = *(const uint4*)(C + (size_t)d0 * TWO_F + F + lane * 8);
    uint4 av1 = *(const uint4*)(C + (size_t)s1 * TWO_F + lane * 8);
    uint4 bv1 = *(const uint4*)(C + (size_t)d1 * TWO_F + F + lane * 8);
    float4 w0 = *(const float4*)(w2 + lane * 8);
    float4 w1 = *(const float4*)(w2 + lane * 8 + 4);

    float sum0, sum1;
    sum0  = w0.x * fmaxf(blo(av0.x) + blo(bv0.x), 0.f);
    sum0 += w0.y * fmaxf(rawf(av0.x) + rawf(bv0.x), 0.f);
    sum0 += w0.z * fmaxf(blo(av0.y) + blo(bv0.y), 0.f);
    sum0 += w0.w * fmaxf(rawf(av0.y) + rawf(bv0.y), 0.f);
    sum0 += w1.x * fmaxf(blo(av0.z) + blo(bv0.z), 0.f);
    sum0 += w1.y * fmaxf(rawf(av0.z) + rawf(bv0.z), 0.f);
    sum0 += w1.z * fmaxf(blo(av0.w) + blo(bv0.w), 0.f);
    sum0 += w1.w * fmaxf(rawf(av0.w) + rawf(bv0.w), 0.f);

    sum1  = w0.x * fmaxf(blo(av1.x) + blo(bv1.x), 0.f);
    sum1 += w0.y * fmaxf(rawf(av1.x) + rawf(bv1.x), 0.f);
    sum1 += w0.z * fmaxf(blo(av1.y) + blo(bv1.y), 0.f);
    sum1 += w0.w * fmaxf(rawf(av1.y) + rawf(bv1.y), 0.f);
    sum1 += w1.x * fmaxf(blo(av1.z) + blo(bv1.z), 0.f);
    sum1 += w1.y * fmaxf(rawf(av1.z) + rawf(bv1.z), 0.f);
    sum1 += w1.z * fmaxf(blo(av1.w) + blo(bv1.w), 0.f);
    sum1 += w1.w * fmaxf(rawf(av1.w) + rawf(bv1.w), 0.f);

    #pragma unroll
    for (int off = 16; off > 0; off >>= 1) {
        sum0 += __shfl_down(sum0, off, 32);
        sum1 += __shfl_down(sum1, off, 32);
    }

    if (lane == 0) {
        float b = b2[0];
        out[e0]     = sum0 + b;
        out[e0 + 1] = sum1 + b;
    }
}

extern "C" void kernel_launch(void* const* d_in, const int* in_sizes, int n_in,
                              void* d_out, int out_size, void* d_ws, size_t ws_size,
                              hipStream_t stream) {
    const float* h    = (const float*)d_in[0];
    const int*   src  = (const int*)d_in[1];
    const int*   dst  = (const int*)d_in[2];
    const float* W1_w = (const float*)d_in[3];
    const float* W1_b = (const float*)d_in[4];
    const float* W2_w = (const float*)d_in[5];
    const float* W2_b = (const float*)d_in[6];
    float* out = (float*)d_out;

    const int M = in_sizes[0] / F;   // 50000
    const int E = in_sizes[1];       // 800000

    // ws: [Wb bf16 256KB][pad to 512KB][hb bf16 25.6MB, pad to 26MB][C bf16 51.2MB]
    unsigned short* Wb = (unsigned short*)d_ws;
    unsigned short* hb = (unsigned short*)((char*)d_ws + 512 * 1024);
    unsigned short* C  = (unsigned short*)((char*)d_ws + 512 * 1024 + 26 * 1024 * 1024);

    int prep_threads = M * 128 > TWO_F * F ? M * 128 : TWO_F * F;
    prep_kernel<<<(prep_threads + 255) / 256, 256, 0, stream>>>(h, W1_w, hb, Wb, M);

    // grid: 392 m-chunks x 8 n-blocks, XCD-paired encoding
    int nbx = ((M + BM - 1) / BM + 7) / 8 * 8;     // 392
    gemm_kernel<<<nbx * 8, 256, 0, stream>>>(hb, Wb, W1_b, C, M);

    edge_kernel<<<(E / 2 + 7) / 8, 256, 0, stream>>>(C, src, dst, W2_w, W2_b, out, E);
}